// Round 9
// baseline (85.011 us; speedup 1.0000x reference)
//
#include <hip/hip_runtime.h>
#include <stdint.h>

#define NSEQ   1536
#define NBATCH 4
#define NM     (NBATCH * NSEQ)   // 6144
#define DMODEL 512
#define NHEAD  8
#define HD     64
#define TBLN   2047              // 2*1024-1

typedef __attribute__((ext_vector_type(4))) float  f32x4;
typedef __attribute__((ext_vector_type(4))) int    i32x4;
typedef __attribute__((ext_vector_type(8))) __bf16 bf16x8;
typedef unsigned short u16;

static_assert(sizeof(bf16x8) == 16, "bf16x8 must be 16B");

__device__ inline u16 f2bf(float f) {
  union { float f; uint32_t u; } v; v.f = f;
  uint32_t u = v.u;
  return (u16)((u + 0x7fffu + ((u >> 16) & 1u)) >> 16);   // RNE
}

__device__ inline bf16x8 ld_bf8(const u16* p) {
  i32x4 v = *(const i32x4*)p;
  return __builtin_bit_cast(bf16x8, v);
}

__device__ inline f32x4 mfma16(bf16x8 a, bf16x8 b, f32x4 c) {
  return __builtin_amdgcn_mfma_f32_16x16x32_bf16(a, b, c, 0, 0, 0);
}

__device__ inline void gload_lds16(const void* g, void* l) {
  __builtin_amdgcn_global_load_lds(
      (__attribute__((address_space(1))) void*)(g),
      (__attribute__((address_space(3))) void*)(l), 16, 0, 0);
}

__device__ inline uint32_t pkbf(float a, float b) {
  uint32_t r;
  asm("v_cvt_pk_bf16_f32 %0, %1, %2" : "=v"(r) : "v"(a), "v"(b));
  return r;   // lo16 = bf16(a), hi16 = bf16(b)
}

__device__ inline float exp2_raw(float x) {   // |x| small: no libm guards
  float r;
  asm("v_exp_f32 %0, %1" : "=v"(r) : "v"(x));
  return r;
}

// ---------------------------------------------------------------- LayerNorm
__global__ __launch_bounds__(256) void ln_kernel(
    const float* __restrict__ vis, const float* __restrict__ txt,
    const float* __restrict__ gamma, const float* __restrict__ beta,
    u16* __restrict__ zn) {
  const int lane = threadIdx.x & 63;
  const int row  = blockIdx.x * 4 + (threadIdx.x >> 6);
  const int b = row / NSEQ, n = row - b * NSEQ;
  const float* src = (n < 1024) ? (vis + ((size_t)b * 1024 + n) * DMODEL)
                                : (txt + ((size_t)b * 512 + (n - 1024)) * DMODEL);
  const float4* s4 = (const float4*)src;
  float4 x0 = s4[lane], x1 = s4[lane + 64];
  float s = x0.x + x0.y + x0.z + x0.w + x1.x + x1.y + x1.z + x1.w;
  float q = x0.x*x0.x + x0.y*x0.y + x0.z*x0.z + x0.w*x0.w
          + x1.x*x1.x + x1.y*x1.y + x1.z*x1.z + x1.w*x1.w;
  #pragma unroll
  for (int m = 1; m < 64; m <<= 1) { s += __shfl_xor(s, m); q += __shfl_xor(q, m); }
  const float mean = s * (1.0f / 512.0f);
  const float var  = q * (1.0f / 512.0f) - mean * mean;
  const float rstd = rsqrtf(var + 1e-5f);
  const float4* g4 = (const float4*)gamma;
  const float4* b4 = (const float4*)beta;
  float4 g0 = g4[lane], g1 = g4[lane + 64], p0 = b4[lane], p1 = b4[lane + 64];
  u16* dst = zn + (size_t)row * DMODEL;
  ushort4 o0, o1;
  o0.x = f2bf((x0.x - mean) * rstd * g0.x + p0.x);
  o0.y = f2bf((x0.y - mean) * rstd * g0.y + p0.y);
  o0.z = f2bf((x0.z - mean) * rstd * g0.z + p0.z);
  o0.w = f2bf((x0.w - mean) * rstd * g0.w + p0.w);
  o1.x = f2bf((x1.x - mean) * rstd * g1.x + p1.x);
  o1.y = f2bf((x1.y - mean) * rstd * g1.y + p1.y);
  o1.z = f2bf((x1.z - mean) * rstd * g1.z + p1.z);
  o1.w = f2bf((x1.w - mean) * rstd * g1.w + p1.w);
  *(ushort4*)(dst + lane * 4)        = o0;
  *(ushort4*)(dst + (lane + 64) * 4) = o1;
}

// ------------------------------------------------- weight transpose -> bf16
__global__ __launch_bounds__(256) void wtrans_kernel(
    const float* __restrict__ WQ, const float* __restrict__ WK,
    const float* __restrict__ WV, const float* __restrict__ WO,
    u16* __restrict__ wqkvt, u16* __restrict__ wot) {
  __shared__ float t[32][33];
  const int m = blockIdx.z;
  const float* W = (m == 0) ? WQ : (m == 1) ? WK : (m == 2) ? WV : WO;
  const int n0 = blockIdx.x * 32, k0 = blockIdx.y * 32;
  const int tx = threadIdx.x & 31, ty = threadIdx.x >> 5;
  #pragma unroll
  for (int j = 0; j < 4; ++j)
    t[ty + j * 8][tx] = W[(size_t)(k0 + ty + j * 8) * DMODEL + n0 + tx];
  __syncthreads();
  u16* out = (m < 3) ? (wqkvt + (size_t)m * DMODEL * DMODEL) : wot;
  #pragma unroll
  for (int j = 0; j < 4; ++j)
    out[(size_t)(n0 + ty + j * 8) * DMODEL + k0 + tx] = f2bf(t[tx][ty + j * 8]);
}

// ------------------------------------------------------------- QKV GEMM
// 128(M) x 96(N) tile, BK=64, 4 waves (2x2), wave tile 64x48.
// grid 16x48 = 768 blocks = exactly 3 per CU (balanced).
__global__ __launch_bounds__(256) void gemm_qkv(
    const u16* __restrict__ A, const u16* __restrict__ Bt,
    const float* __restrict__ bQ, const float* __restrict__ bK, const float* __restrict__ bV,
    u16* __restrict__ Q, u16* __restrict__ Kk, u16* __restrict__ Vt) {
  __shared__ __align__(16) u16 lat[128 * 64];
  __shared__ __align__(16) u16 lbt[96 * 64];
  const int tid = threadIdx.x, lane = tid & 63, w = tid >> 6;
  const int wr = w >> 1, wc = w & 1;
  const int m0 = blockIdx.y * 128, n0 = blockIdx.x * 96;
  f32x4 acc[4][3] = {};
  for (int kt = 0; kt < 8; ++kt) {
    const int k0 = kt * 64;
    #pragma unroll
    for (int i = 0; i < 4; ++i) {
      int ch = tid + 256 * i;                 // A: 1024 chunks
      int row = ch >> 3, pc = ch & 7;
      int kk = k0 + ((pc ^ (row & 7)) << 3);
      gload_lds16(A + (size_t)(m0 + row) * DMODEL + kk, lat + (size_t)ch * 8);
    }
    #pragma unroll
    for (int i = 0; i < 3; ++i) {
      int ch = tid + 256 * i;                 // B: 768 chunks
      int row = ch >> 3, pc = ch & 7;
      int kk = k0 + ((pc ^ (row & 7)) << 3);
      gload_lds16(Bt + (size_t)(n0 + row) * DMODEL + kk, lbt + (size_t)ch * 8);
    }
    __syncthreads();
    #pragma unroll
    for (int ks = 0; ks < 2; ++ks) {
      bf16x8 af[4], bfr[3];
      const int cc = ks * 4 + (lane >> 4);
      #pragma unroll
      for (int f = 0; f < 4; ++f) {
        int ra = wr * 64 + f * 16 + (lane & 15);
        af[f]  = ld_bf8(lat + ra * 64 + ((cc ^ (ra & 7)) << 3));
      }
      #pragma unroll
      for (int f = 0; f < 3; ++f) {
        int rb = wc * 48 + f * 16 + (lane & 15);
        bfr[f] = ld_bf8(lbt + rb * 64 + ((cc ^ (rb & 7)) << 3));
      }
      #pragma unroll
      for (int fr = 0; fr < 4; ++fr)
        #pragma unroll
        for (int fc = 0; fc < 3; ++fc)
          acc[fr][fc] = mfma16(af[fr], bfr[fc], acc[fr][fc]);
    }
    __syncthreads();
  }
  #pragma unroll
  for (int fr = 0; fr < 4; ++fr) {
    const int mbase = m0 + wr * 64 + fr * 16 + ((lane >> 4) << 2);
    const int b = mbase / NSEQ;
    const int nseq = mbase - b * NSEQ;
    #pragma unroll
    for (int fc = 0; fc < 3; ++fc) {
      const int col = n0 + wc * 48 + fc * 16 + (lane & 15);
      const int which = col >> 9;
      const int cw = col & 511;
      const int h = cw >> 6, d = cw & 63;
      const float bias = (which == 0) ? bQ[cw] : (which == 1) ? bK[cw] : bV[cw];
      if (which < 2) {
        u16* dst = ((which == 0) ? Q : Kk) + ((size_t)(b * NHEAD + h) * NSEQ + nseq) * HD + d;
        #pragma unroll
        for (int r = 0; r < 4; ++r) dst[(size_t)r * HD] = f2bf(acc[fr][fc][r] + bias);
      } else {
        ushort4 pv;
        pv.x = f2bf(acc[fr][fc][0] + bias);
        pv.y = f2bf(acc[fr][fc][1] + bias);
        pv.z = f2bf(acc[fr][fc][2] + bias);
        pv.w = f2bf(acc[fr][fc][3] + bias);
        *(ushort4*)(Vt + ((size_t)(b * NHEAD + h) * HD + d) * NSEQ + nseq) = pv;
      }
    }
  }
}

// ------------------------------------------------------------ O-proj GEMM
// 64x64 tile, 4 waves (2x2), wave tile 32x32. grid 8x96 = 768 blocks (3/CU).
__global__ __launch_bounds__(256) void gemm_oproj(
    const u16* __restrict__ A, const u16* __restrict__ Bt,
    const float* __restrict__ bO, float* __restrict__ out) {
  __shared__ __align__(16) u16 lat[64 * 64];
  __shared__ __align__(16) u16 lbt[64 * 64];
  const int tid = threadIdx.x, lane = tid & 63, w = tid >> 6;
  const int wr = w >> 1, wc = w & 1;
  const int m0 = blockIdx.y * 64, n0 = blockIdx.x * 64;
  f32x4 acc[2][2] = {};
  for (int kt = 0; kt < 8; ++kt) {
    const int k0 = kt * 64;
    #pragma unroll
    for (int i = 0; i < 2; ++i) {
      int ch = tid + 256 * i;                 // 512 chunks each
      int row = ch >> 3, pc = ch & 7;
      int kk = k0 + ((pc ^ (row & 7)) << 3);
      gload_lds16(A  + (size_t)(m0 + row) * DMODEL + kk, lat + (size_t)ch * 8);
      gload_lds16(Bt + (size_t)(n0 + row) * DMODEL + kk, lbt + (size_t)ch * 8);
    }
    __syncthreads();
    #pragma unroll
    for (int ks = 0; ks < 2; ++ks) {
      bf16x8 af[2], bfr[2];
      const int cc = ks * 4 + (lane >> 4);
      #pragma unroll
      for (int f = 0; f < 2; ++f) {
        int ra = wr * 32 + f * 16 + (lane & 15);
        af[f]  = ld_bf8(lat + ra * 64 + ((cc ^ (ra & 7)) << 3));
        int rb = wc * 32 + f * 16 + (lane & 15);
        bfr[f] = ld_bf8(lbt + rb * 64 + ((cc ^ (rb & 7)) << 3));
      }
      #pragma unroll
      for (int fr = 0; fr < 2; ++fr)
        #pragma unroll
        for (int fc = 0; fc < 2; ++fc)
          acc[fr][fc] = mfma16(af[fr], bfr[fc], acc[fr][fc]);
    }
    __syncthreads();
  }
  #pragma unroll
  for (int fr = 0; fr < 2; ++fr) {
    const int mbase = m0 + wr * 32 + fr * 16 + ((lane >> 4) << 2);
    #pragma unroll
    for (int fc = 0; fc < 2; ++fc) {
      const int col = n0 + wc * 32 + fc * 16 + (lane & 15);
      const float bias = bO[col];
      float* dst = out + (size_t)mbase * DMODEL + col;
      #pragma unroll
      for (int r = 0; r < 4; ++r) dst[(size_t)r * DMODEL] = acc[fr][fc][r] + bias;
    }
  }
}

// ------------------------------------------------------------- attention v9
// = v8 (128-k phases, dbuf, counted vmcnt(8), two independent 64-k halves,
// setprio) + the missing END-OF-ITERATION arrival barrier: with only 2
// buffers, the read of buf[cur] must complete (all waves) before kt+1's
// STAGE overwrites it. By barrier arrival every ds_read result is already
// consumed by MFMAs (compiler lgkmcnt), so no drain needed; stage(kt+1)
// stays in flight across both barriers.
__global__ __launch_bounds__(384, 2) void attn_kernel(
    const u16* __restrict__ Q, const u16* __restrict__ K,
    const u16* __restrict__ Vt, const float* __restrict__ table,
    u16* __restrict__ O) {
  __shared__ float rblds[3072];                   // 12 KB reversed bias (log2)
  __shared__ __align__(16) u16 kbuf[2][8192];     // 32 KB (128k x 64d)
  __shared__ __align__(16) u16 vbuf[2][8192];     // 32 KB (64d x 128k)
  __shared__ __align__(16) u16 plds[6][4096];     // 48 KB (wave-private, 2 halves)
  const int tid = threadIdx.x, lane = tid & 63, w = tid >> 6;
  const int bid = blockIdx.x;
  const int xcd = bid & 7, idx = bid >> 3;        // idx in [0,32)
  const int bh  = xcd * 4 + (idx & 3);
  const int qt  = idx >> 2;                       // [0,8)
  const int h   = bh & (NHEAD - 1);
  // rblds[t] = table[clamp(2558 - t, 0, 2046)][h] * log2(e)
  for (int t = tid; t < 3072; t += 384) {
    int src = 2558 - t;
    src = src < 0 ? 0 : (src > 2046 ? 2046 : src);
    rblds[t] = table[(size_t)src * NHEAD + h] * 1.4426950408889634f;
  }

  const int lo16 = lane & 15, g = lane >> 4;
  const int q0 = qt * 192 + w * 32;
  const u16* Qb = Q  + (size_t)bh * NSEQ * HD;
  const u16* Kb = K  + (size_t)bh * NSEQ * HD;
  const u16* Vb = Vt + (size_t)bh * HD * NSEQ;

  // staging (tid<256): 128-k tile = K 1024 chunks + V 1024 chunks, 8/thread.
  // K: LDS chunk ch holds global chunk row*8 + ((ch&7)^(row&7)), row=k (128).
  // V: LDS chunk ch holds global chunk row*16 + ((ch&8)|((ch^row)&7)), row=d.
#define STAGE2(buf, k0)                                                        \
  if (tid < 256) {                                                             \
    _Pragma("unroll")                                                          \
    for (int i = 0; i < 4; ++i) {                                              \
      int ch = tid + 256 * i;                                                  \
      int krow = ch >> 3;                                                      \
      int kcol = ((ch ^ krow) & 7) << 3;                                       \
      gload_lds16(Kb + (size_t)((k0) + krow) * HD + kcol, kbuf[buf] + (size_t)ch * 8); \
      int vrow = ch >> 4;                                                      \
      int vcg  = (ch & 8) | ((ch ^ vrow) & 7);                                 \
      gload_lds16(Vb + (size_t)vrow * NSEQ + (k0) + vcg * 8, vbuf[buf] + (size_t)ch * 8); \
    }                                                                          \
  }

  bf16x8 qf[2][2];
  #pragma unroll
  for (int s = 0; s < 2; ++s)
    #pragma unroll
    for (int kd = 0; kd < 2; ++kd)
      qf[s][kd] = ld_bf8(Qb + (size_t)(q0 + s * 16 + lo16) * HD + kd * 32 + g * 8);

  float l_part[2] = {0.f, 0.f};
  f32x4 acc[2][4] = {};

  char* plb = (char*)plds[w];            // 8 KB: half hh at +4096, subtile s at +2048
  const int pswz  = (lo16 & 7) << 4;
  const int wbase = lo16 * 128;
  const int rswz  = lo16 & 7;
  // bias: value(hh,s,kc,r) = rbp[k0 + hh*64 + 16*(kc - s + 1) + r]
  const float* rbp = rblds + (1535 - q0 - lo16 + 4 * g - 16);
  const float c1 = 0.125f * 1.4426950408889634f;   // scale * log2(e)

  STAGE2(0, 0);
  __syncthreads();                       // once: bias writes + stage0 drain
  int cur = 0;

  for (int kt = 0; kt < 12; ++kt) {
    const int k0 = kt * 128;
    const int nxt = cur ^ 1;
    if (kt < 11) {
      STAGE2(nxt, k0 + 128);
      if (tid < 256) asm volatile("s_waitcnt vmcnt(8)" ::: "memory");
    } else {
      if (tid < 256) asm volatile("s_waitcnt vmcnt(0)" ::: "memory");
    }
    __builtin_amdgcn_s_barrier();        // stage(kt) visible; stage(kt+1) in flight
    const u16* kb = kbuf[cur];
    const u16* vb = vbuf[cur];
    #pragma unroll
    for (int hh = 0; hh < 2; ++hh) {
      char* plh = plb + hh * 4096;
      // ---- bias groups (consecutive per-lane indices)
      float bvg[5][4];
      #pragma unroll
      for (int j = 0; j < 5; ++j)
        #pragma unroll
        for (int r = 0; r < 4; ++r)
          bvg[j][r] = rbp[k0 + hh * 64 + 16 * j + r];
      // ---- S^T = K . Q^T for both subtiles
      f32x4 st[2][4] = {};
      __builtin_amdgcn_s_setprio(1);
      #pragma unroll
      for (int kc = 0; kc < 4; ++kc) {
        const int row = hh * 64 + kc * 16 + lo16;
        const bf16x8 kf0 = ld_bf8(kb + row * 64 + ((g ^ rswz) << 3));
        const bf16x8 kf1 = ld_bf8(kb + row * 64 + (((4 + g) ^ rswz) << 3));
        #pragma unroll
        for (int s = 0; s < 2; ++s) {
          st[s][kc] = mfma16(kf0, qf[s][0], st[s][kc]);
          st[s][kc] = mfma16(kf1, qf[s][1], st[s][kc]);
        }
      }
      __builtin_amdgcn_s_setprio(0);
      // ---- p = 2^(s*c1 + bias'); lane-local l; pack to P slab
      #pragma unroll
      for (int s = 0; s < 2; ++s)
        #pragma unroll
        for (int kc = 0; kc < 4; ++kc) {
          #pragma unroll
          for (int r = 0; r < 4; ++r) {
            float p = exp2_raw(__builtin_fmaf(st[s][kc][r], c1, bvg[kc - s + 1][r]));
            st[s][kc][r] = p;
            l_part[s] += p;
          }
          uint2 pr;
          pr.x = pkbf(st[s][kc][0], st[s][kc][1]);
          pr.y = pkbf(st[s][kc][2], st[s][kc][3]);
          *(uint2*)(plh + s * 2048 + wbase + ((kc * 32 + g * 8) ^ pswz)) = pr;
        }
      // ---- PV: V frag chunk = hh*8 | ((t*4+g)^rswz); each frag feeds 2 MFMA
      __builtin_amdgcn_s_setprio(1);
      #pragma unroll
      for (int t = 0; t < 2; ++t) {
        bf16x8 pb[2];
        #pragma unroll
        for (int s = 0; s < 2; ++s)
          pb[s] = ld_bf8((const u16*)(plh + s * 2048 + wbase + ((t * 64 + g * 16) ^ pswz)));
        #pragma unroll
        for (int fc = 0; fc < 4; ++fc) {
          const int row = fc * 16 + lo16;
          const int cl = (hh * 8) | (((t * 4 + g) ^ rswz) & 7);
          const bf16x8 vf = ld_bf8(vb + row * 128 + cl * 8);
          #pragma unroll
          for (int s = 0; s < 2; ++s)
            acc[s][fc] = mfma16(vf, pb[s], acc[s][fc]);
        }
      }
      __builtin_amdgcn_s_setprio(0);
    }
    __builtin_amdgcn_s_barrier();        // all reads of buf[cur] done before overwrite
    cur = nxt;
  }
  // ---- epilogue per subtile
  const int b = bh >> 3;
  #pragma unroll
  for (int s = 0; s < 2; ++s) {
    float l_r = l_part[s];
    l_r += __shfl_xor(l_r, 16);
    l_r += __shfl_xor(l_r, 32);
    const float inv = 1.0f / l_r;
    u16* orow = O + ((size_t)(b * NSEQ + q0 + s * 16 + lo16)) * DMODEL + h * HD;
    #pragma unroll
    for (int fc = 0; fc < 4; ++fc) {
      uint2 o4;
      o4.x = pkbf(acc[s][fc][0] * inv, acc[s][fc][1] * inv);
      o4.y = pkbf(acc[s][fc][2] * inv, acc[s][fc][3] * inv);
      *(uint2*)(orow + fc * 16 + g * 4) = o4;
    }
  }
#undef STAGE2
}

// ---------------------------------------------------------------- launch
extern "C" void kernel_launch(void* const* d_in, const int* in_sizes, int n_in,
                              void* d_out, int out_size, void* d_ws, size_t ws_size,
                              hipStream_t stream) {
  const float* vis   = (const float*)d_in[0];
  const float* txt   = (const float*)d_in[1];
  const float* WQ    = (const float*)d_in[2];
  const float* bQ    = (const float*)d_in[3];
  const float* WK    = (const float*)d_in[4];
  const float* bK    = (const float*)d_in[5];
  const float* WV    = (const float*)d_in[6];
  const float* bV    = (const float*)d_in[7];
  const float* WO    = (const float*)d_in[8];
  const float* bO    = (const float*)d_in[9];
  const float* table = (const float*)d_in[10];
  const float* gamma = (const float*)d_in[11];
  const float* beta  = (const float*)d_in[12];
  float* out = (float*)d_out;

  char* p = (char*)d_ws;
  u16* zn    = (u16*)p; p += (size_t)NM * DMODEL * 2;
  u16* wqkvt = (u16*)p; p += (size_t)3 * DMODEL * DMODEL * 2;
  u16* wot   = (u16*)p; p += (size_t)DMODEL * DMODEL * 2;
  u16* q     = (u16*)p; p += (size_t)NM * DMODEL * 2;
  u16* k     = (u16*)p; p += (size_t)NM * DMODEL * 2;
  u16* vt    = (u16*)p; p += (size_t)NM * DMODEL * 2;
  u16* o     = (u16*)p; p += (size_t)NM * DMODEL * 2;

  hipLaunchKernelGGL(ln_kernel, dim3(NM / 4), dim3(256), 0, stream,
                     vis, txt, gamma, beta, zn);
  hipLaunchKernelGGL(wtrans_kernel, dim3(16, 16, 4), dim3(256), 0, stream,
                     WQ, WK, WV, WO, wqkvt, wot);
  hipLaunchKernelGGL(gemm_qkv, dim3(16, 48), dim3(256), 0, stream,
                     zn, wqkvt, bQ, bK, bV, q, k, vt);
  hipLaunchKernelGGL(attn_kernel, dim3(256), dim3(384), 0, stream,
                     q, k, vt, table, o);
  hipLaunchKernelGGL(gemm_oproj, dim3(8, 96), dim3(256), 0, stream,
                     o, wot, bO, out);
}